// Round 7
// baseline (35.696 us; speedup 1.0000x reference)
//
#include <hip/hip_runtime.h>
#include <math.h>

#define TT 16
#define HH 48
#define WW 48
#define CC 64
#define DD 6
#define VS (TT*HH*WW)     // 36864 voxels
#define SS (HH*WW)        // 2304 queries
#define NST (VS/32)       // 1152 supertiles of 32 voxels
#define NCH 128           // voxel chunks
#define SPC (NST/NCH)     // 9 supertiles per chunk
#define QPB 128           // queries per block (4 waves x 32)
#define NQB (SS/QPB)      // 18 query blocks
#define LOG2E 1.44269504088896f

typedef float    f4   __attribute__((ext_vector_type(4)));
typedef float    f16v __attribute__((ext_vector_type(16)));
typedef _Float16 h8   __attribute__((ext_vector_type(8)));
typedef int      i4   __attribute__((ext_vector_type(4)));

// Workspace layout per supertile: 192 f4 slots = [A:64][G_w0:64][G_w1:64]
//  A slot l (l<32): voxel stbase+l, 8 f16 = feats 0-5 + 2 zeros; l>=32: zeros
//    (= exact A-frag of mfma_32x32x16: A[row=l&31][k=8*(l>>5)+j], feats 8-15 zero)
//  G_w slot l: h=l>>5, c=l&31: c<4 ? coords of voxels stbase+16w+8h+j : 0
//    (= exact A-frag for MFMA2: A[row=coord c][k=vox 8h+j] within window w)

// ---------------- Kernel A: projection + LN + fragment packing ----------------
__global__ __launch_bounds__(256) void proj_kernel(
    const float* __restrict__ vol, const float* __restrict__ slc,
    const float* __restrict__ w2d, const float* __restrict__ b2d,
    const float* __restrict__ g2d, const float* __restrict__ be2d,
    const float* __restrict__ w3d, const float* __restrict__ b3d,
    const float* __restrict__ g3d, const float* __restrict__ be3d,
    f4* __restrict__ Kf4, f4* __restrict__ Qh4)
{
    int tid = threadIdx.x;
    int gid = blockIdx.x * 256 + tid;

    bool isK = gid < VS;
    const float *src, *wgt, *bia, *gam, *bet;
    int pos, stride;
    if (isK) { src = vol; wgt = w3d; bia = b3d; gam = g3d; bet = be3d; pos = gid;      stride = VS; }
    else     { src = slc; wgt = w2d; bia = b2d; gam = g2d; bet = be2d; pos = gid - VS; stride = SS; }

    float y[DD];
    {
        float acc[DD] = {0.f,0.f,0.f,0.f,0.f,0.f};
        for (int c = 0; c < CC; ++c) {
            float x = src[c * stride + pos];
            #pragma unroll
            for (int d = 0; d < DD; ++d) acc[d] = fmaf(wgt[d*CC + c], x, acc[d]);
        }
        float mu = 0.f;
        #pragma unroll
        for (int d = 0; d < DD; ++d) { acc[d] += bia[d]; mu += acc[d]; }
        mu *= (1.f/DD);
        float var = 0.f;
        #pragma unroll
        for (int d = 0; d < DD; ++d) { float t = acc[d] - mu; var = fmaf(t, t, var); }
        var *= (1.f/DD);
        float inv = rsqrtf(var + 1e-5f);
        #pragma unroll
        for (int d = 0; d < DD; ++d) y[d] = (acc[d] - mu) * inv * gam[d] + bet[d];
    }

    if (isK) {
        int stl = tid >> 5, r = tid & 31;
        int stg = blockIdx.x * 8 + stl;
        h8 kh = (h8){ (_Float16)y[0], (_Float16)y[1], (_Float16)y[2],
                      (_Float16)y[3], (_Float16)y[4], (_Float16)y[5],
                      (_Float16)0.f, (_Float16)0.f };
        Kf4[(size_t)stg*192 + r]      = __builtin_bit_cast(f4, kh);
        Kf4[(size_t)stg*192 + 32 + r] = (f4){0.f,0.f,0.f,0.f};

        // G lines: 8 supertiles * 2 windows * 64 lanes = 1024 slots per block
        for (int s = tid; s < 1024; s += 256) {
            int ss  = s >> 7;
            int rem = s & 127;
            int w   = rem >> 6;
            int l   = rem & 63;
            int h   = l >> 5, c = l & 31;
            h8 gh = (h8){0,0,0,0,0,0,0,0};
            if (c < 4) {
                int vb = (blockIdx.x*8 + ss)*32 + w*16 + h*8;
                #pragma unroll
                for (int j = 0; j < 8; ++j) {
                    int v  = vb + j;
                    int t  = v / (HH*WW);
                    int rm = v - t*(HH*WW);
                    int hh = rm / WW;
                    int ww = rm - hh*WW;
                    float val = (c==0) ? (float)t - 7.5f
                              : (c==1) ? (float)hh - 23.5f
                              : (c==2) ? (float)ww - 23.5f
                              :          1.0f;
                    gh[j] = (_Float16)val;
                }
            }
            Kf4[(size_t)(blockIdx.x*8 + ss)*192 + 64 + w*64 + l] = __builtin_bit_cast(f4, gh);
        }
    } else {
        h8 qh = (h8){ (_Float16)(y[0]*LOG2E), (_Float16)(y[1]*LOG2E),
                      (_Float16)(y[2]*LOG2E), (_Float16)(y[3]*LOG2E),
                      (_Float16)(y[4]*LOG2E), (_Float16)(y[5]*LOG2E),
                      (_Float16)0.f, (_Float16)0.f };
        Qh4[pos] = __builtin_bit_cast(f4, qh);
    }
}

// ---------------- Kernel B: 32x32 MFMA attention ----------------
// Block = 4 waves; wave owns 32 queries, streams 9 supertiles (32 vox each).
// Per supertile: MFMA1 (32x32x16_f16) -> 16x exp2 -> pack+half-swap -> 2x MFMA2.
// D1[vox][q]: col=l&31=q, vox=(reg&3)+8*(reg>>2)+4*(l>>5).
// A2-window map: reg r=4m+i at half h -> window w=m>>1, dest-half m&1, j=4h+i.
__global__ __launch_bounds__(256) void attn_kernel(
    const f4* __restrict__ Kf4, const f4* __restrict__ Qh4,
    f4* __restrict__ Pc4)
{
    int tid  = threadIdx.x;
    int wv   = tid >> 6;
    int lane = tid & 63;
    int q31  = lane & 31;
    bool lo  = lane < 32;
    int qb   = blockIdx.x / NCH;
    int ch   = blockIdx.x - qb*NCH;
    int qbase = qb*QPB + wv*32;

    // B1 Q-frag: lane holds Q[feats 8h+j][query q31]; h=1 half is zero
    f4 qv = (f4){0.f,0.f,0.f,0.f};
    if (lo) qv = Qh4[qbase + q31];
    h8 qf = __builtin_bit_cast(h8, qv);

    f16v acc = {};
    const f4* kp = Kf4 + (size_t)ch*SPC*192 + lane;

    f4 va = kp[0], g0 = kp[64], g1 = kp[128];
    for (int it = 0; it < SPC; ++it) {
        f4 vaN, g0N, g1N;
        if (it + 1 < SPC) {
            const f4* kn = kp + (it+1)*192;
            vaN = kn[0]; g0N = kn[64]; g1N = kn[128];
        }
        // logits for 32 vox x 32 queries
        f16v s = __builtin_amdgcn_mfma_f32_32x32x16_f16(
                     __builtin_bit_cast(h8, va), qf, (f16v){}, 0, 0, 0);
        float p[16];
        #pragma unroll
        for (int r = 0; r < 16; ++r) p[r] = __builtin_amdgcn_exp2f(s[r]);
        int U[8];
        #pragma unroll
        for (int m = 0; m < 4; ++m) {
            U[2*m]   = __builtin_bit_cast(int, __builtin_amdgcn_cvt_pkrtz(p[4*m],   p[4*m+1]));
            U[2*m+1] = __builtin_bit_cast(int, __builtin_amdgcn_cvt_pkrtz(p[4*m+2], p[4*m+3]));
        }
        #pragma unroll
        for (int w = 0; w < 2; ++w) {
            int a0 = U[4*w+0], a1 = U[4*w+1];
            int b0 = U[4*w+2], b1 = U[4*w+3];
            int a0s = __shfl_xor(a0, 32), b0s = __shfl_xor(b0, 32);
            int a1s = __shfl_xor(a1, 32), b1s = __shfl_xor(b1, 32);
            i4 pi;
            pi.x = lo ? a0  : b0s;   // reg jj0: k-pair (8h+0, 8h+1)
            pi.y = lo ? a1  : b1s;   // jj1: (8h+2, 8h+3)
            pi.z = lo ? a0s : b0;    // jj2: (8h+4, 8h+5)
            pi.w = lo ? a1s : b1;    // jj3: (8h+6, 8h+7)
            h8 pf = __builtin_bit_cast(h8, pi);
            h8 gf = __builtin_bit_cast(h8, (w == 0) ? g0 : g1);
            // D2[coord][q] += G[coord][vox] * P[vox][q]
            acc = __builtin_amdgcn_mfma_f32_32x32x16_f16(gf, pf, acc, 0, 0, 0);
        }
        va = vaN; g0 = g0N; g1 = g1N;
    }
    // D2: col=l&31=q; rows 0-3 (ct,ch,cw,sum) live in regs 0-3 of lanes<32
    if (lo) {
        f4 o = (f4){acc[0], acc[1], acc[2], acc[3]};
        Pc4[(size_t)(qbase + q31)*NCH + ch] = o;
    }
}

// ---------------- Kernel C: merge chunks, finalize flow ----------------
__global__ __launch_bounds__(256) void final_kernel(
    const f4* __restrict__ Pc4, float* __restrict__ out)
{
    int wv   = threadIdx.x >> 6;
    int lane = threadIdx.x & 63;
    int q = blockIdx.x * 4 + wv;

    f4 a = Pc4[(size_t)q*NCH + lane] + Pc4[(size_t)q*NCH + 64 + lane];

    #pragma unroll
    for (int off = 32; off >= 1; off >>= 1) {
        a.x += __shfl_xor(a.x, off);
        a.y += __shfl_xor(a.y, off);
        a.z += __shfl_xor(a.z, off);
        a.w += __shfl_xor(a.w, off);
    }
    if (lane == 0) {
        float inv = 1.f / a.w;
        int h = q / WW;
        int w = q - h*WW;
        out[q]        = a.x * inv;                        // t (slice grid t = 0)
        out[SS + q]   = a.y * inv - ((float)h - 23.5f);   // h
        out[2*SS + q] = a.z * inv - ((float)w - 23.5f);   // w
    }
}

extern "C" void kernel_launch(void* const* d_in, const int* in_sizes, int n_in,
                              void* d_out, int out_size, void* d_ws, size_t ws_size,
                              hipStream_t stream)
{
    const float* vol  = (const float*)d_in[0];
    const float* slc  = (const float*)d_in[1];
    const float* w2d  = (const float*)d_in[2];
    const float* b2d  = (const float*)d_in[3];
    const float* g2d  = (const float*)d_in[4];
    const float* be2d = (const float*)d_in[5];
    const float* w3d  = (const float*)d_in[6];
    const float* b3d  = (const float*)d_in[7];
    const float* g3d  = (const float*)d_in[8];
    const float* be3d = (const float*)d_in[9];
    float* out = (float*)d_out;

    // ws: Kf (1152*192*16B = 3.54MB) | Qh (2304*16B) | Pc (2304*128*16B = 4.72MB)
    f4* Kf4 = (f4*)d_ws;
    f4* Qh4 = Kf4 + (size_t)NST*192;
    f4* Pc4 = Qh4 + SS;

    proj_kernel<<<(VS + SS)/256, 256, 0, stream>>>(vol, slc, w2d, b2d, g2d, be2d,
                                                   w3d, b3d, g3d, be3d, Kf4, Qh4);
    attn_kernel<<<NQB*NCH, 256, 0, stream>>>(Kf4, Qh4, Pc4);
    final_kernel<<<SS/4, 256, 0, stream>>>(Pc4, out);
}